// Round 15
// baseline (179.167 us; speedup 1.0000x reference)
//
#include <hip/hip_runtime.h>
#include <stdint.h>

#define N_NODES 2048
#define N_EDGES 4096
#define N_GRAPH 16
#define IN_DIM  11
#define HID     128
#define E_DIMF  6
#define EDGE_H  64
#define NSLICE  65            // 64 h-slices + 1 bias slice
#define ZCOLS   (NSLICE*HID)  // 8320
#define BN_EPS  1e-5f

typedef __attribute__((ext_vector_type(8))) short short8;
typedef __attribute__((ext_vector_type(4))) float f32x4;

static __device__ __forceinline__ float bf2f(unsigned short u) {
  union { float f; uint32_t i; } x; x.i = ((uint32_t)u) << 16; return x.f;
}
static __device__ __forceinline__ unsigned short f2bf(float f) {
  union { float f; uint32_t i; } x; x.f = f;
  uint32_t i = x.i;
  return (unsigned short)((i + 0x7FFFu + ((i >> 16) & 1u)) >> 16);
}

// direct global->LDS DMA, 16B per lane. LDS dest must be base+lane*16 (linear).
static __device__ __forceinline__ void gload_lds16(const void* g, void* l) {
  __builtin_amdgcn_global_load_lds(
      (const __attribute__((address_space(1))) uint32_t*)g,
      (__attribute__((address_space(3))) uint32_t*)l, 16, 0, 0);
}

struct PrepP {
  const float *eW2_0, *eb2_0, *eW2, *eb2, *h_in;
  const int *dst;
  unsigned short *WbT0, *WbTL, *xb0;
  int *roff, *cursor, *nodeorder;
  float *gsum;
  unsigned int *gmax;
  float *gcnt;
};

// ==== prep_all: CSR+degsort(block 0) + vectorized transposes + xb0 + zero =====
#define PREP_BLOCKS 270
__global__ __launch_bounds__(256) void prep_all(PrepP p) {
  const int bid = blockIdx.x, t = threadIdx.x;
  __shared__ union {
    struct { int hist[N_NODES]; int part[256]; } csr;       // 9 KB
    unsigned short tile[128 * 130];                          // 33.3 KB
  } sm;

  if (bid == 0) {
    // ---- deg histogram + exclusive scan -> roff, cursor ----
    for (int i = t; i < N_NODES; i += 256) sm.csr.hist[i] = 0;
    __syncthreads();
    for (int e = t; e < N_EDGES; e += 256) atomicAdd(&sm.csr.hist[p.dst[e]], 1);
    __syncthreads();
    const int base = t * 8;
    int loc[8];
    int s = 0;
#pragma unroll
    for (int j = 0; j < 8; ++j) { loc[j] = s; s += sm.csr.hist[base + j]; }
    sm.csr.part[t] = s;
    __syncthreads();
    for (int d = 1; d < 256; d <<= 1) {  // Hillis-Steele inclusive scan
      int v = sm.csr.part[t];
      if (t >= d) v += sm.csr.part[t - d];
      __syncthreads();
      sm.csr.part[t] = v;
      __syncthreads();
    }
    const int pre = (t == 0) ? 0 : sm.csr.part[t - 1];
#pragma unroll
    for (int j = 0; j < 8; ++j) {
      p.roff[base + j] = pre + loc[j];
      p.cursor[base + j] = pre + loc[j];
    }
    if (t == 255) p.roff[N_NODES] = pre + s;
    __syncthreads();
    // ---- degree counting sort -> nodeorder (balanced gather blocks) ----
    if (t < 32) sm.csr.part[t] = 0;
    __syncthreads();
    for (int i = t; i < N_NODES; i += 256)
      atomicAdd(&sm.csr.part[min(sm.csr.hist[i], 31)], 1);
    __syncthreads();
    if (t == 0) {
      int run = 0;
#pragma unroll
      for (int b = 0; b < 32; ++b) { int c = sm.csr.part[b]; sm.csr.part[b] = run; run += c; }
    }
    __syncthreads();
    for (int i = t; i < N_NODES; i += 256) {
      int pos = atomicAdd(&sm.csr.part[min(sm.csr.hist[i], 31)], 1);
      p.nodeorder[pos] = i;
    }
  } else if (bid <= 260) {
    // ---- transpose one W2 slab -> WbT [(k,o)][i] bf16 (vectorized) ----
    const int s = bid - 1;
    if (s < 65) {  // layer 0, KP=32, din=11
      const int k = s;
      const float* srcp = (k < 64) ? (p.eW2_0 + (size_t)k * IN_DIM * HID) : p.eb2_0;
      for (int j4 = t; j4 < IN_DIM * HID / 4; j4 += 256) {   // float4 reads
        const float4 v = *(const float4*)(srcp + j4 * 4);
        const int i = j4 >> 5, o = (j4 & 31) * 4;
        sm.tile[i * 130 + o + 0] = f2bf(v.x);
        sm.tile[i * 130 + o + 1] = f2bf(v.y);
        sm.tile[i * 130 + o + 2] = f2bf(v.z);
        sm.tile[i * 130 + o + 3] = f2bf(v.w);
      }
      __syncthreads();
      for (int c = t; c < HID * 32 / 8; c += 256) {          // short8 writes
        const int o = c >> 2, i0 = (c & 3) * 8;
        short8 pk;
#pragma unroll
        for (int u = 0; u < 8; ++u)
          pk[u] = (i0 + u < IN_DIM) ? (short)sm.tile[(i0 + u) * 130 + o] : (short)0;
        *(short8*)(p.WbT0 + ((size_t)k * HID + o) * 32 + i0) = pk;
      }
    } else {  // layers 1..3, KP=128
      const int sl = s - 65, l = sl / 65, k = sl % 65;
      const float* srcp = (k < 64) ? (p.eW2 + ((size_t)l * 64 + k) * (HID * HID))
                                   : (p.eb2 + (size_t)l * (HID * HID));
      unsigned short* dstp = p.WbTL + (size_t)l * ZCOLS * HID;
      for (int j4 = t; j4 < HID * HID / 4; j4 += 256) {      // float4 reads
        const float4 v = *(const float4*)(srcp + j4 * 4);
        const int i = j4 >> 5, o = (j4 & 31) * 4;
        sm.tile[i * 130 + o + 0] = f2bf(v.x);
        sm.tile[i * 130 + o + 1] = f2bf(v.y);
        sm.tile[i * 130 + o + 2] = f2bf(v.z);
        sm.tile[i * 130 + o + 3] = f2bf(v.w);
      }
      __syncthreads();
      for (int c = t; c < HID * HID / 8; c += 256) {         // short8 writes
        const int o = c >> 4, i0 = (c & 15) * 8;
        short8 pk;
#pragma unroll
        for (int u = 0; u < 8; ++u) pk[u] = (short)sm.tile[(i0 + u) * 130 + o];
        *(short8*)(dstp + ((size_t)k * HID + o) * HID + i0) = pk;
      }
    }
  } else if (bid <= 268) {
    // ---- layer-0 input cast -> bf16 padded [N][32] ----
    for (int idx = (bid - 261) * 256 + t; idx < N_NODES * 32; idx += 8 * 256) {
      int n = idx >> 5, i = idx & 31;
      p.xb0[idx] = f2bf(i < IN_DIM ? p.h_in[n * IN_DIM + i] : 0.f);
    }
  } else {
    // ---- zero accumulators ----
    for (int i = t; i < N_GRAPH * HID; i += 256) {
      p.gsum[i] = 0.f;
      p.gmax[i] = 0u;
    }
    if (t < N_GRAPH) p.gcnt[t] = 0.f;
  }
}

// ------- Z GEMM (R11 body) + fused scatter row + XCD-chunked block swizzle ----
// compute rows: flat = y*65+x in [0,1040); 1040 % 8 == 0 -> bijective chunked
// remap (each XCD gets a contiguous 130-block range -> nb/B-slab L2 locality).
template <int KP, int SWZ, int SCAT>
__global__ __launch_bounds__(256) void gemm_z(
    const unsigned short* __restrict__ Xb, const unsigned short* __restrict__ WbT,
    unsigned short* __restrict__ Z,
    const int* __restrict__ dst, const int* __restrict__ srcv,
    const float* __restrict__ efeat, int* __restrict__ cursor,
    int* __restrict__ esrc, float* __restrict__ ef6) {
  if (SCAT && blockIdx.y == 16) {
    const int e = blockIdx.x * 256 + threadIdx.x;
    if (e < N_EDGES) {
      float ef[E_DIMF];
#pragma unroll
      for (int j = 0; j < E_DIMF; ++j) ef[j] = efeat[e * E_DIMF + j];
      const int se = srcv[e];
      const int pos = atomicAdd(&cursor[dst[e]], 1);
      esrc[pos] = se;
#pragma unroll
      for (int j = 0; j < E_DIMF; ++j) ef6[pos * E_DIMF + j] = ef[j];
    }
    return;
  }
  extern __shared__ unsigned short lds[];
  unsigned short* Al = lds;
  unsigned short* Bl = lds + 128 * KP;
  const int flat = blockIdx.y * 65 + blockIdx.x;          // [0, 1040)
  const int swz = (flat & 7) * 130 + (flat >> 3);         // bijective (1040%8==0)
  const int nb = swz % 65;
  const int mb = swz / 65;
  const int t = threadIdx.x;
  const int ROWB = KP * 2;
  const int NCH = 128 * ROWB / 16;
  const unsigned short* Asrc = Xb + (size_t)mb * 128 * KP;
  const unsigned short* Bsrc = WbT + (size_t)nb * 128 * KP;
  for (int c = t; c < NCH; c += 256) {
    const int d = c * 16;                 // linear LDS dest (lane-consecutive)
    const int row = d / ROWB;
    const int s = d ^ ((row & SWZ) << 4); // inverse-swizzled global source
    gload_lds16((const char*)Asrc + s, (char*)Al + d);
    gload_lds16((const char*)Bsrc + s, (char*)Bl + d);
  }
  __syncthreads();
  const int w = t >> 6, l = t & 63;
  const int wm = (w >> 1) * 64, wn = (w & 1) * 64;
  const int lr = l & 15, lh = l >> 4;
  f32x4 acc[4][4] = {};
#pragma unroll
  for (int kk = 0; kk < KP; kk += 32) {
    short8 a[4], b[4];
    const int kb = (kk + lh * 8) * 2;
#pragma unroll
    for (int mi = 0; mi < 4; ++mi) {
      int row = wm + mi * 16 + lr;
      int addr = row * ROWB + (kb ^ ((row & SWZ) << 4));
      a[mi] = *(const short8*)((const char*)Al + addr);
    }
#pragma unroll
    for (int ni = 0; ni < 4; ++ni) {
      int col = wn + ni * 16 + lr;
      int addr = col * ROWB + (kb ^ ((col & SWZ) << 4));
      b[ni] = *(const short8*)((const char*)Bl + addr);
    }
#pragma unroll
    for (int mi = 0; mi < 4; ++mi)
#pragma unroll
      for (int ni = 0; ni < 4; ++ni)
        acc[mi][ni] = __builtin_amdgcn_mfma_f32_16x16x32_bf16(b[ni], a[mi], acc[mi][ni], 0, 0, 0);
  }
#pragma unroll
  for (int mi = 0; mi < 4; ++mi) {
    const int node = mb * 128 + wm + mi * 16 + lr;
    unsigned short* zp = Z + (size_t)node * ZCOLS + nb * 128 + wn + lh * 4;
#pragma unroll
    for (int ni = 0; ni < 4; ++ni) {
      ushort4 pk;
      pk.x = f2bf(acc[mi][ni][0]);
      pk.y = f2bf(acc[mi][ni][1]);
      pk.z = f2bf(acc[mi][ni][2]);
      pk.w = f2bf(acc[mi][ni][3]);
      *(ushort4*)(zp + ni * 16) = pk;
    }
  }
}

// ------- per-node gather: 4 deg-sorted nodes/block, 512 threads ---------------
// per node (128 threads): cg2 = tt&15 (8 channels), kg = tt>>4 (8 k).
// W1/b1 hoisted; next-edge esrc/ef6 prefetched. Same per-node FMA order as
// R13 -> bit-identical output.
template <int LAST>
__global__ __launch_bounds__(512) void node_gather(
    const float* __restrict__ ef6, const float* __restrict__ W1,
    const float* __restrict__ b1, const unsigned short* __restrict__ Z,
    const int* __restrict__ esrc, const int* __restrict__ roff,
    const int* __restrict__ nodeorder,
    const float* __restrict__ bias, const float* __restrict__ gamma,
    const float* __restrict__ beta, const float* __restrict__ mean,
    const float* __restrict__ var,
    unsigned short* __restrict__ xbout,
    const int* __restrict__ ng, float* __restrict__ gsum,
    unsigned int* __restrict__ gmax, float* __restrict__ gcnt) {
  const int t = threadIdx.x;
  const int hh = t >> 7, tt = t & 127;
  const int n = nodeorder[blockIdx.x * 4 + hh];  // deg-sorted: balanced quads
  const int cg2 = tt & 15, kg = tt >> 4;
  const int start = roff[n], end = roff[n + 1];
  __shared__ float red[4][128][9];

  // hoist this thread's W1 column block + b1 into registers (edge-invariant)
  float w1r[E_DIMF][8], b1r[8];
#pragma unroll
  for (int kk = 0; kk < 8; ++kk) {
    const int k = kg * 8 + kk;
    b1r[kk] = b1[k];
#pragma unroll
    for (int j = 0; j < E_DIMF; ++j) w1r[j][kk] = W1[j * EDGE_H + k];
  }

  float acc8[8] = {};
  int se_nx = 0;
  float ef_nx[E_DIMF];
  if (start < end) {
    se_nx = esrc[start];
#pragma unroll
    for (int j = 0; j < E_DIMF; ++j) ef_nx[j] = ef6[start * E_DIMF + j];
  }
  for (int idx = start; idx < end; ++idx) {
    const int se = se_nx;
    float ef[E_DIMF];
#pragma unroll
    for (int j = 0; j < E_DIMF; ++j) ef[j] = ef_nx[j];
    if (idx + 1 < end) {  // prefetch next edge while this one computes
      se_nx = esrc[idx + 1];
#pragma unroll
      for (int j = 0; j < E_DIMF; ++j) ef_nx[j] = ef6[(idx + 1) * E_DIMF + j];
    }
    float hk[8];
#pragma unroll
    for (int kk = 0; kk < 8; ++kk) {
      float a = b1r[kk];
#pragma unroll
      for (int j = 0; j < E_DIMF; ++j) a += ef[j] * w1r[j][kk];
      hk[kk] = fmaxf(a, 0.f);
    }
    const unsigned short* zr = Z + (size_t)se * ZCOLS + cg2 * 8;
#pragma unroll
    for (int kk = 0; kk < 8; ++kk) {
      short8 v = *(const short8*)(zr + (kg * 8 + kk) * HID);
      const float hv = hk[kk];
#pragma unroll
      for (int j = 0; j < 8; ++j) acc8[j] += hv * bf2f((unsigned short)v[j]);
    }
    if (kg == 0) {  // bias slice k=64, h=1
      short8 v = *(const short8*)(zr + 64 * HID);
#pragma unroll
      for (int j = 0; j < 8; ++j) acc8[j] += bf2f((unsigned short)v[j]);
    }
  }
#pragma unroll
  for (int j = 0; j < 8; ++j) red[hh][tt][j] = acc8[j];
  __syncthreads();
  const int o = tt;
  float s = 0.f;
#pragma unroll
  for (int k2 = 0; k2 < 8; ++k2) s += red[hh][k2 * 16 + (o >> 3)][o & 7];
  const int dg = end - start;
  float v = s / (float)(dg > 0 ? dg : 1) + bias[o];
  v = fmaxf(v, 0.f);
  v = (v - mean[o]) * rsqrtf(var[o] + BN_EPS) * gamma[o] + beta[o];
  if (!LAST) {
    xbout[n * HID + o] = f2bf(v);
  } else {
    const int g = ng[n];
    atomicAdd(&gsum[g * HID + o], v);
    unsigned int u = __float_as_uint(v);
    unsigned int key = (u & 0x80000000u) ? ~u : (u | 0x80000000u);
    atomicMax(&gmax[g * HID + o], key);
    if (o == 0) atomicAdd(&gcnt[g], 1.f);
  }
}

// ---------------- output BN + max decode ----------------
__global__ void out_final(const float* __restrict__ gsum, const unsigned int* __restrict__ gmax,
                          const float* __restrict__ gcnt,
                          const float* __restrict__ g_out, const float* __restrict__ b_out,
                          const float* __restrict__ m_out, const float* __restrict__ v_out,
                          float* __restrict__ out) {
  int g = blockIdx.x, t = threadIdx.x;
  float hn = gsum[g * HID + t] / fmaxf(gcnt[g], 1.0f);
  hn = (hn - m_out[t]) * rsqrtf(v_out[t] + BN_EPS) * g_out[t] + b_out[t];
  unsigned int key = gmax[g * HID + t];
  unsigned int u = (key & 0x80000000u) ? (key ^ 0x80000000u) : ~key;
  out[g * 2 * HID + t] = hn;
  out[g * 2 * HID + HID + t] = __uint_as_float(u);
}

// ================================ host ========================================

extern "C" void kernel_launch(void* const* d_in, const int* in_sizes, int n_in,
                              void* d_out, int out_size, void* d_ws, size_t ws_size,
                              hipStream_t stream) {
  const float* h_in   = (const float*)d_in[0];
  const float* e_in   = (const float*)d_in[1];
  const int*   src    = (const int*)d_in[2];
  const int*   dst    = (const int*)d_in[3];
  const int*   ng     = (const int*)d_in[4];
  const float* eW1_0  = (const float*)d_in[5];
  const float* eb1_0  = (const float*)d_in[6];
  const float* eW2_0  = (const float*)d_in[7];
  const float* eb2_0  = (const float*)d_in[8];
  const float* bias_0 = (const float*)d_in[9];
  const float* gamma_0= (const float*)d_in[10];
  const float* beta_0 = (const float*)d_in[11];
  const float* mean_0 = (const float*)d_in[12];
  const float* var_0  = (const float*)d_in[13];
  const float* eW1    = (const float*)d_in[14];
  const float* eb1    = (const float*)d_in[15];
  const float* eW2    = (const float*)d_in[16];
  const float* eb2    = (const float*)d_in[17];
  const float* biasL  = (const float*)d_in[18];
  const float* gammaL = (const float*)d_in[19];
  const float* betaL  = (const float*)d_in[20];
  const float* meanL  = (const float*)d_in[21];
  const float* varL   = (const float*)d_in[22];
  const float* g_out  = (const float*)d_in[23];
  const float* b_out  = (const float*)d_in[24];
  const float* m_out  = (const float*)d_in[25];
  const float* v_out  = (const float*)d_in[26];
  float* out = (float*)d_out;

  char* ws = (char*)d_ws;
  size_t off = 0;
  auto alloc = [&](size_t bytes) {
    void* pp = ws + off;
    off = (off + bytes + 255) & ~(size_t)255;
    return pp;
  };
  unsigned short* Z    = (unsigned short*)alloc((size_t)N_NODES * ZCOLS * 2);
  unsigned short* WbT0 = (unsigned short*)alloc((size_t)ZCOLS * 32 * 2);
  unsigned short* WbTL = (unsigned short*)alloc((size_t)3 * ZCOLS * HID * 2);
  unsigned short* xb0  = (unsigned short*)alloc((size_t)N_NODES * 32 * 2);
  unsigned short* xb   = (unsigned short*)alloc((size_t)N_NODES * HID * 2);
  float* gsum          = (float*)alloc((size_t)N_GRAPH * HID * 4);
  unsigned int* gmax   = (unsigned int*)alloc((size_t)N_GRAPH * HID * 4);
  float* gcnt          = (float*)alloc((size_t)N_GRAPH * 4);
  int* roff            = (int*)alloc((size_t)(N_NODES + 1) * 4);
  int* cursor          = (int*)alloc((size_t)N_NODES * 4);
  int* nodeorder       = (int*)alloc((size_t)N_NODES * 4);
  int* esrc            = (int*)alloc((size_t)N_EDGES * 4);
  float* ef6           = (float*)alloc((size_t)N_EDGES * E_DIMF * 4);

  PrepP P;
  P.eW2_0 = eW2_0; P.eb2_0 = eb2_0; P.eW2 = eW2; P.eb2 = eb2; P.h_in = h_in;
  P.dst = dst;
  P.WbT0 = WbT0; P.WbTL = WbTL; P.xb0 = xb0;
  P.roff = roff; P.cursor = cursor; P.nodeorder = nodeorder;
  P.gsum = gsum; P.gmax = gmax; P.gcnt = gcnt;

  // node 1: prep (CSR offsets + deg-sort, transposes, xb0, zero)
  prep_all<<<PREP_BLOCKS, 256, 0, stream>>>(P);

  // node 2: layer-0 gemm + fused scatter/pre-gather (grid.y==16 row)
  gemm_z<32, 3, 1><<<dim3(65, 17), 256, 2 * 128 * 32 * 2, stream>>>(
      xb0, WbT0, Z, dst, src, e_in, cursor, esrc, ef6);
  // node 3: layer-0 gather
  node_gather<0><<<N_NODES / 4, 512, 0, stream>>>(ef6, eW1_0, eb1_0, Z, esrc, roff,
                                                  nodeorder, bias_0, gamma_0, beta_0,
                                                  mean_0, var_0, xb, ng, gsum, gmax, gcnt);

  // nodes 4-9: layers 1..3
  for (int l = 0; l < 3; ++l) {
    gemm_z<128, 7, 0><<<dim3(65, 16), 256, 2 * 128 * 128 * 2, stream>>>(
        xb, WbTL + (size_t)l * ZCOLS * HID, Z, nullptr, nullptr, nullptr,
        nullptr, nullptr, nullptr);
    if (l < 2)
      node_gather<0><<<N_NODES / 4, 512, 0, stream>>>(
          ef6, eW1 + l * E_DIMF * EDGE_H, eb1 + l * EDGE_H, Z, esrc, roff,
          nodeorder, biasL + l * HID, gammaL + l * HID, betaL + l * HID,
          meanL + l * HID, varL + l * HID, xb, ng, gsum, gmax, gcnt);
    else
      node_gather<1><<<N_NODES / 4, 512, 0, stream>>>(
          ef6, eW1 + l * E_DIMF * EDGE_H, eb1 + l * EDGE_H, Z, esrc, roff,
          nodeorder, biasL + l * HID, gammaL + l * HID, betaL + l * HID,
          meanL + l * HID, varL + l * HID, xb, ng, gsum, gmax, gcnt);
  }

  // node 10: readout finale
  out_final<<<N_GRAPH, HID, 0, stream>>>(gsum, gmax, gcnt, g_out, b_out, m_out,
                                         v_out, out);
}

// Round 16
// 170.991 us; speedup vs baseline: 1.0478x; 1.0478x over previous
//
#include <hip/hip_runtime.h>
#include <stdint.h>

#define N_NODES 2048
#define N_EDGES 4096
#define N_GRAPH 16
#define IN_DIM  11
#define HID     128
#define E_DIMF  6
#define EDGE_H  64
#define NSLICE  65            // 64 h-slices + 1 bias slice
#define ZCOLS   (NSLICE*HID)  // 8320
#define BN_EPS  1e-5f

typedef __attribute__((ext_vector_type(8))) short short8;
typedef __attribute__((ext_vector_type(4))) float f32x4;

static __device__ __forceinline__ float bf2f(unsigned short u) {
  union { float f; uint32_t i; } x; x.i = ((uint32_t)u) << 16; return x.f;
}
static __device__ __forceinline__ unsigned short f2bf(float f) {
  union { float f; uint32_t i; } x; x.f = f;
  uint32_t i = x.i;
  return (unsigned short)((i + 0x7FFFu + ((i >> 16) & 1u)) >> 16);
}

// direct global->LDS DMA, 16B per lane. LDS dest must be base+lane*16 (linear).
static __device__ __forceinline__ void gload_lds16(const void* g, void* l) {
  __builtin_amdgcn_global_load_lds(
      (const __attribute__((address_space(1))) uint32_t*)g,
      (__attribute__((address_space(3))) uint32_t*)l, 16, 0, 0);
}

struct PrepP {
  const float *eW2_0, *eb2_0, *eW2, *eb2, *h_in;
  const int *dst;
  unsigned short *WbT0, *WbTL, *xb0;
  int *roff, *cursor, *nodeorder;
  float *gsum;
  unsigned int *gmax;
  float *gcnt;
};

// ==== prep_all: CSR+degsort(block 0) + vectorized transposes + xb0 + zero =====
#define PREP_BLOCKS 270
__global__ __launch_bounds__(256) void prep_all(PrepP p) {
  const int bid = blockIdx.x, t = threadIdx.x;
  __shared__ union {
    struct { int hist[N_NODES]; int part[256]; } csr;       // 9 KB
    unsigned short tile[128 * 130];                          // 33.3 KB
  } sm;

  if (bid == 0) {
    // ---- deg histogram + exclusive scan -> roff, cursor ----
    for (int i = t; i < N_NODES; i += 256) sm.csr.hist[i] = 0;
    __syncthreads();
    for (int e = t; e < N_EDGES; e += 256) atomicAdd(&sm.csr.hist[p.dst[e]], 1);
    __syncthreads();
    const int base = t * 8;
    int loc[8];
    int s = 0;
#pragma unroll
    for (int j = 0; j < 8; ++j) { loc[j] = s; s += sm.csr.hist[base + j]; }
    sm.csr.part[t] = s;
    __syncthreads();
    for (int d = 1; d < 256; d <<= 1) {  // Hillis-Steele inclusive scan
      int v = sm.csr.part[t];
      if (t >= d) v += sm.csr.part[t - d];
      __syncthreads();
      sm.csr.part[t] = v;
      __syncthreads();
    }
    const int pre = (t == 0) ? 0 : sm.csr.part[t - 1];
#pragma unroll
    for (int j = 0; j < 8; ++j) {
      p.roff[base + j] = pre + loc[j];
      p.cursor[base + j] = pre + loc[j];
    }
    if (t == 255) p.roff[N_NODES] = pre + s;
    __syncthreads();
    // ---- degree counting sort -> nodeorder (balanced gather blocks) ----
    if (t < 32) sm.csr.part[t] = 0;
    __syncthreads();
    for (int i = t; i < N_NODES; i += 256)
      atomicAdd(&sm.csr.part[min(sm.csr.hist[i], 31)], 1);
    __syncthreads();
    if (t == 0) {
      int run = 0;
#pragma unroll
      for (int b = 0; b < 32; ++b) { int c = sm.csr.part[b]; sm.csr.part[b] = run; run += c; }
    }
    __syncthreads();
    for (int i = t; i < N_NODES; i += 256) {
      int pos = atomicAdd(&sm.csr.part[min(sm.csr.hist[i], 31)], 1);
      p.nodeorder[pos] = i;
    }
  } else if (bid <= 260) {
    // ---- transpose one W2 slab -> WbT [(k,o)][i] bf16 (vectorized) ----
    const int s = bid - 1;
    if (s < 65) {  // layer 0, KP=32, din=11
      const int k = s;
      const float* srcp = (k < 64) ? (p.eW2_0 + (size_t)k * IN_DIM * HID) : p.eb2_0;
      for (int j4 = t; j4 < IN_DIM * HID / 4; j4 += 256) {   // float4 reads
        const float4 v = *(const float4*)(srcp + j4 * 4);
        const int i = j4 >> 5, o = (j4 & 31) * 4;
        sm.tile[i * 130 + o + 0] = f2bf(v.x);
        sm.tile[i * 130 + o + 1] = f2bf(v.y);
        sm.tile[i * 130 + o + 2] = f2bf(v.z);
        sm.tile[i * 130 + o + 3] = f2bf(v.w);
      }
      __syncthreads();
      for (int c = t; c < HID * 32 / 8; c += 256) {          // short8 writes
        const int o = c >> 2, i0 = (c & 3) * 8;
        short8 pk;
#pragma unroll
        for (int u = 0; u < 8; ++u)
          pk[u] = (i0 + u < IN_DIM) ? (short)sm.tile[(i0 + u) * 130 + o] : (short)0;
        *(short8*)(p.WbT0 + ((size_t)k * HID + o) * 32 + i0) = pk;
      }
    } else {  // layers 1..3, KP=128
      const int sl = s - 65, l = sl / 65, k = sl % 65;
      const float* srcp = (k < 64) ? (p.eW2 + ((size_t)l * 64 + k) * (HID * HID))
                                   : (p.eb2 + (size_t)l * (HID * HID));
      unsigned short* dstp = p.WbTL + (size_t)l * ZCOLS * HID;
      for (int j4 = t; j4 < HID * HID / 4; j4 += 256) {      // float4 reads
        const float4 v = *(const float4*)(srcp + j4 * 4);
        const int i = j4 >> 5, o = (j4 & 31) * 4;
        sm.tile[i * 130 + o + 0] = f2bf(v.x);
        sm.tile[i * 130 + o + 1] = f2bf(v.y);
        sm.tile[i * 130 + o + 2] = f2bf(v.z);
        sm.tile[i * 130 + o + 3] = f2bf(v.w);
      }
      __syncthreads();
      for (int c = t; c < HID * HID / 8; c += 256) {         // short8 writes
        const int o = c >> 4, i0 = (c & 15) * 8;
        short8 pk;
#pragma unroll
        for (int u = 0; u < 8; ++u) pk[u] = (short)sm.tile[(i0 + u) * 130 + o];
        *(short8*)(dstp + ((size_t)k * HID + o) * HID + i0) = pk;
      }
    }
  } else if (bid <= 268) {
    // ---- layer-0 input cast -> bf16 padded [N][32] ----
    for (int idx = (bid - 261) * 256 + t; idx < N_NODES * 32; idx += 8 * 256) {
      int n = idx >> 5, i = idx & 31;
      p.xb0[idx] = f2bf(i < IN_DIM ? p.h_in[n * IN_DIM + i] : 0.f);
    }
  } else {
    // ---- zero accumulators ----
    for (int i = t; i < N_GRAPH * HID; i += 256) {
      p.gsum[i] = 0.f;
      p.gmax[i] = 0u;
    }
    if (t < N_GRAPH) p.gcnt[t] = 0.f;
  }
}

// ---------------- Z GEMM (R11 body) + fused scatter row ----------------------
template <int KP, int SWZ, int SCAT>
__global__ __launch_bounds__(256) void gemm_z(
    const unsigned short* __restrict__ Xb, const unsigned short* __restrict__ WbT,
    unsigned short* __restrict__ Z,
    const int* __restrict__ dst, const int* __restrict__ srcv,
    const float* __restrict__ efeat, int* __restrict__ cursor,
    int* __restrict__ esrc, float* __restrict__ ef6) {
  if (SCAT && blockIdx.y == 16) {
    const int e = blockIdx.x * 256 + threadIdx.x;
    if (e < N_EDGES) {
      float ef[E_DIMF];
#pragma unroll
      for (int j = 0; j < E_DIMF; ++j) ef[j] = efeat[e * E_DIMF + j];
      const int se = srcv[e];
      const int pos = atomicAdd(&cursor[dst[e]], 1);
      esrc[pos] = se;
#pragma unroll
      for (int j = 0; j < E_DIMF; ++j) ef6[pos * E_DIMF + j] = ef[j];
    }
    return;
  }
  extern __shared__ unsigned short lds[];
  unsigned short* Al = lds;
  unsigned short* Bl = lds + 128 * KP;
  const int nb = blockIdx.x;
  const int mb = blockIdx.y;
  const int t = threadIdx.x;
  const int ROWB = KP * 2;
  const int NCH = 128 * ROWB / 16;
  const unsigned short* Asrc = Xb + (size_t)mb * 128 * KP;
  const unsigned short* Bsrc = WbT + (size_t)nb * 128 * KP;
  for (int c = t; c < NCH; c += 256) {
    const int d = c * 16;                 // linear LDS dest (lane-consecutive)
    const int row = d / ROWB;
    const int s = d ^ ((row & SWZ) << 4); // inverse-swizzled global source
    gload_lds16((const char*)Asrc + s, (char*)Al + d);
    gload_lds16((const char*)Bsrc + s, (char*)Bl + d);
  }
  __syncthreads();
  const int w = t >> 6, l = t & 63;
  const int wm = (w >> 1) * 64, wn = (w & 1) * 64;
  const int lr = l & 15, lh = l >> 4;
  f32x4 acc[4][4] = {};
#pragma unroll
  for (int kk = 0; kk < KP; kk += 32) {
    short8 a[4], b[4];
    const int kb = (kk + lh * 8) * 2;
#pragma unroll
    for (int mi = 0; mi < 4; ++mi) {
      int row = wm + mi * 16 + lr;
      int addr = row * ROWB + (kb ^ ((row & SWZ) << 4));
      a[mi] = *(const short8*)((const char*)Al + addr);
    }
#pragma unroll
    for (int ni = 0; ni < 4; ++ni) {
      int col = wn + ni * 16 + lr;
      int addr = col * ROWB + (kb ^ ((col & SWZ) << 4));
      b[ni] = *(const short8*)((const char*)Bl + addr);
    }
#pragma unroll
    for (int mi = 0; mi < 4; ++mi)
#pragma unroll
      for (int ni = 0; ni < 4; ++ni)
        acc[mi][ni] = __builtin_amdgcn_mfma_f32_16x16x32_bf16(b[ni], a[mi], acc[mi][ni], 0, 0, 0);
  }
#pragma unroll
  for (int mi = 0; mi < 4; ++mi) {
    const int node = mb * 128 + wm + mi * 16 + lr;
    unsigned short* zp = Z + (size_t)node * ZCOLS + nb * 128 + wn + lh * 4;
#pragma unroll
    for (int ni = 0; ni < 4; ++ni) {
      ushort4 pk;
      pk.x = f2bf(acc[mi][ni][0]);
      pk.y = f2bf(acc[mi][ni][1]);
      pk.z = f2bf(acc[mi][ni][2]);
      pk.w = f2bf(acc[mi][ni][3]);
      *(ushort4*)(zp + ni * 16) = pk;
    }
  }
}

// ------- per-node gather (R13 body) + degree-balanced node assignment ---------
template <int LAST>
__global__ __launch_bounds__(256) void node_gather(
    const float* __restrict__ ef6, const float* __restrict__ W1,
    const float* __restrict__ b1, const unsigned short* __restrict__ Z,
    const int* __restrict__ esrc, const int* __restrict__ roff,
    const int* __restrict__ nodeorder,
    const float* __restrict__ bias, const float* __restrict__ gamma,
    const float* __restrict__ beta, const float* __restrict__ mean,
    const float* __restrict__ var,
    unsigned short* __restrict__ xbout,
    const int* __restrict__ ng, float* __restrict__ gsum,
    unsigned int* __restrict__ gmax, float* __restrict__ gcnt) {
  const int t = threadIdx.x;
  const int hh = t >> 7, tt = t & 127;
  const int n = nodeorder[blockIdx.x * 2 + hh];  // deg-sorted: paired nodes balanced
  const int cg2 = tt & 15, kg = tt >> 4;
  const int start = roff[n], end = roff[n + 1];
  __shared__ float red[2][128][9];

  // hoist this thread's W1 column block + b1 into registers (edge-invariant)
  float w1r[E_DIMF][8], b1r[8];
#pragma unroll
  for (int kk = 0; kk < 8; ++kk) {
    const int k = kg * 8 + kk;
    b1r[kk] = b1[k];
#pragma unroll
    for (int j = 0; j < E_DIMF; ++j) w1r[j][kk] = W1[j * EDGE_H + k];
  }

  float acc8[8] = {};
  int se_nx = 0;
  float ef_nx[E_DIMF];
  if (start < end) {
    se_nx = esrc[start];
#pragma unroll
    for (int j = 0; j < E_DIMF; ++j) ef_nx[j] = ef6[start * E_DIMF + j];
  }
  for (int idx = start; idx < end; ++idx) {
    const int se = se_nx;
    float ef[E_DIMF];
#pragma unroll
    for (int j = 0; j < E_DIMF; ++j) ef[j] = ef_nx[j];
    if (idx + 1 < end) {  // prefetch next edge while this one computes
      se_nx = esrc[idx + 1];
#pragma unroll
      for (int j = 0; j < E_DIMF; ++j) ef_nx[j] = ef6[(idx + 1) * E_DIMF + j];
    }
    float hk[8];
#pragma unroll
    for (int kk = 0; kk < 8; ++kk) {
      float a = b1r[kk];
#pragma unroll
      for (int j = 0; j < E_DIMF; ++j) a += ef[j] * w1r[j][kk];
      hk[kk] = fmaxf(a, 0.f);
    }
    const unsigned short* zr = Z + (size_t)se * ZCOLS + cg2 * 8;
#pragma unroll
    for (int kk = 0; kk < 8; ++kk) {
      short8 v = *(const short8*)(zr + (kg * 8 + kk) * HID);
      const float hv = hk[kk];
#pragma unroll
      for (int j = 0; j < 8; ++j) acc8[j] += hv * bf2f((unsigned short)v[j]);
    }
    if (kg == 0) {  // bias slice k=64, h=1
      short8 v = *(const short8*)(zr + 64 * HID);
#pragma unroll
      for (int j = 0; j < 8; ++j) acc8[j] += bf2f((unsigned short)v[j]);
    }
  }
#pragma unroll
  for (int j = 0; j < 8; ++j) red[hh][tt][j] = acc8[j];
  __syncthreads();
  const int o = tt;
  float s = 0.f;
#pragma unroll
  for (int k2 = 0; k2 < 8; ++k2) s += red[hh][k2 * 16 + (o >> 3)][o & 7];
  const int dg = end - start;
  float v = s / (float)(dg > 0 ? dg : 1) + bias[o];
  v = fmaxf(v, 0.f);
  v = (v - mean[o]) * rsqrtf(var[o] + BN_EPS) * gamma[o] + beta[o];
  if (!LAST) {
    xbout[n * HID + o] = f2bf(v);
  } else {
    const int g = ng[n];
    atomicAdd(&gsum[g * HID + o], v);
    unsigned int u = __float_as_uint(v);
    unsigned int key = (u & 0x80000000u) ? ~u : (u | 0x80000000u);
    atomicMax(&gmax[g * HID + o], key);
    if (o == 0) atomicAdd(&gcnt[g], 1.f);
  }
}

// ---------------- output BN + max decode ----------------
__global__ void out_final(const float* __restrict__ gsum, const unsigned int* __restrict__ gmax,
                          const float* __restrict__ gcnt,
                          const float* __restrict__ g_out, const float* __restrict__ b_out,
                          const float* __restrict__ m_out, const float* __restrict__ v_out,
                          float* __restrict__ out) {
  int g = blockIdx.x, t = threadIdx.x;
  float hn = gsum[g * HID + t] / fmaxf(gcnt[g], 1.0f);
  hn = (hn - m_out[t]) * rsqrtf(v_out[t] + BN_EPS) * g_out[t] + b_out[t];
  unsigned int key = gmax[g * HID + t];
  unsigned int u = (key & 0x80000000u) ? (key ^ 0x80000000u) : ~key;
  out[g * 2 * HID + t] = hn;
  out[g * 2 * HID + HID + t] = __uint_as_float(u);
}

// ================================ host ========================================

extern "C" void kernel_launch(void* const* d_in, const int* in_sizes, int n_in,
                              void* d_out, int out_size, void* d_ws, size_t ws_size,
                              hipStream_t stream) {
  const float* h_in   = (const float*)d_in[0];
  const float* e_in   = (const float*)d_in[1];
  const int*   src    = (const int*)d_in[2];
  const int*   dst    = (const int*)d_in[3];
  const int*   ng     = (const int*)d_in[4];
  const float* eW1_0  = (const float*)d_in[5];
  const float* eb1_0  = (const float*)d_in[6];
  const float* eW2_0  = (const float*)d_in[7];
  const float* eb2_0  = (const float*)d_in[8];
  const float* bias_0 = (const float*)d_in[9];
  const float* gamma_0= (const float*)d_in[10];
  const float* beta_0 = (const float*)d_in[11];
  const float* mean_0 = (const float*)d_in[12];
  const float* var_0  = (const float*)d_in[13];
  const float* eW1    = (const float*)d_in[14];
  const float* eb1    = (const float*)d_in[15];
  const float* eW2    = (const float*)d_in[16];
  const float* eb2    = (const float*)d_in[17];
  const float* biasL  = (const float*)d_in[18];
  const float* gammaL = (const float*)d_in[19];
  const float* betaL  = (const float*)d_in[20];
  const float* meanL  = (const float*)d_in[21];
  const float* varL   = (const float*)d_in[22];
  const float* g_out  = (const float*)d_in[23];
  const float* b_out  = (const float*)d_in[24];
  const float* m_out  = (const float*)d_in[25];
  const float* v_out  = (const float*)d_in[26];
  float* out = (float*)d_out;

  char* ws = (char*)d_ws;
  size_t off = 0;
  auto alloc = [&](size_t bytes) {
    void* pp = ws + off;
    off = (off + bytes + 255) & ~(size_t)255;
    return pp;
  };
  unsigned short* Z    = (unsigned short*)alloc((size_t)N_NODES * ZCOLS * 2);
  unsigned short* WbT0 = (unsigned short*)alloc((size_t)ZCOLS * 32 * 2);
  unsigned short* WbTL = (unsigned short*)alloc((size_t)3 * ZCOLS * HID * 2);
  unsigned short* xb0  = (unsigned short*)alloc((size_t)N_NODES * 32 * 2);
  unsigned short* xb   = (unsigned short*)alloc((size_t)N_NODES * HID * 2);
  float* gsum          = (float*)alloc((size_t)N_GRAPH * HID * 4);
  unsigned int* gmax   = (unsigned int*)alloc((size_t)N_GRAPH * HID * 4);
  float* gcnt          = (float*)alloc((size_t)N_GRAPH * 4);
  int* roff            = (int*)alloc((size_t)(N_NODES + 1) * 4);
  int* cursor          = (int*)alloc((size_t)N_NODES * 4);
  int* nodeorder       = (int*)alloc((size_t)N_NODES * 4);
  int* esrc            = (int*)alloc((size_t)N_EDGES * 4);
  float* ef6           = (float*)alloc((size_t)N_EDGES * E_DIMF * 4);

  PrepP P;
  P.eW2_0 = eW2_0; P.eb2_0 = eb2_0; P.eW2 = eW2; P.eb2 = eb2; P.h_in = h_in;
  P.dst = dst;
  P.WbT0 = WbT0; P.WbTL = WbTL; P.xb0 = xb0;
  P.roff = roff; P.cursor = cursor; P.nodeorder = nodeorder;
  P.gsum = gsum; P.gmax = gmax; P.gcnt = gcnt;

  // node 1: prep (CSR offsets + deg-sort, transposes, xb0, zero)
  prep_all<<<PREP_BLOCKS, 256, 0, stream>>>(P);

  // node 2: layer-0 gemm + fused scatter/pre-gather (grid.y==16 row)
  gemm_z<32, 3, 1><<<dim3(65, 17), 256, 2 * 128 * 32 * 2, stream>>>(
      xb0, WbT0, Z, dst, src, e_in, cursor, esrc, ef6);
  // node 3: layer-0 gather
  node_gather<0><<<N_NODES / 2, 256, 0, stream>>>(ef6, eW1_0, eb1_0, Z, esrc, roff,
                                                  nodeorder, bias_0, gamma_0, beta_0,
                                                  mean_0, var_0, xb, ng, gsum, gmax, gcnt);

  // nodes 4-9: layers 1..3
  for (int l = 0; l < 3; ++l) {
    gemm_z<128, 7, 0><<<dim3(65, 16), 256, 2 * 128 * 128 * 2, stream>>>(
        xb, WbTL + (size_t)l * ZCOLS * HID, Z, nullptr, nullptr, nullptr,
        nullptr, nullptr, nullptr);
    if (l < 2)
      node_gather<0><<<N_NODES / 2, 256, 0, stream>>>(
          ef6, eW1 + l * E_DIMF * EDGE_H, eb1 + l * EDGE_H, Z, esrc, roff,
          nodeorder, biasL + l * HID, gammaL + l * HID, betaL + l * HID,
          meanL + l * HID, varL + l * HID, xb, ng, gsum, gmax, gcnt);
    else
      node_gather<1><<<N_NODES / 2, 256, 0, stream>>>(
          ef6, eW1 + l * E_DIMF * EDGE_H, eb1 + l * EDGE_H, Z, esrc, roff,
          nodeorder, biasL + l * HID, gammaL + l * HID, betaL + l * HID,
          meanL + l * HID, varL + l * HID, xb, ng, gsum, gmax, gcnt);
  }

  // node 10: readout finale
  out_final<<<N_GRAPH, HID, 0, stream>>>(gsum, gmax, gcnt, g_out, b_out, m_out,
                                         v_out, out);
}